// Round 8
// baseline (178.176 us; speedup 1.0000x reference)
//
#include <hip/hip_runtime.h>

// MCLLoss: masked L1 loss over 5 overlapping value-ranges of real_img.
// Ranges: (-1,1), (-1,-.5), (-.5,0), (0,.5), (.5,1) — inclusive bounds,
// masks overlap; class_mask takes the LAST matching range index.
// Output layout: [loss, losses[5], class_mask_rescaled[N]]; rescale = cls*0.5-1.
//
// R13: R12's pipeline, but with registers to live in.
// R12 post-mortem: __launch_bounds__(256,8) caps VGPR at 64 -> compiler
// CANNOT hold 3 tiles (48 VGPR) + addressing + accumulators, so it sank all
// loads to their uses (VGPR=28, serial round trips). The duty-cycle theory
// (loads in flight only ~30% of block lifetime -> 2.1 of 6.3 TB/s) was never
// tested. Now: __launch_bounds__(256,4) -> 128 VGPR budget, depth-4 rolling
// pipeline over 8 unconditional tiles. Steady state: 4 tiles (128 B/thread)
// in flight WHILE computing -> ~131 KB/CU continuously in flight (need ~22KB
// by Little's law). Validity check: VGPR must come back >= 60.
// Ledger (R5-R11): total-main = 112±5us fixed harness overhead; main is the
// only lever. Partials: plain-store SoA + vectorized final (R10), no memset.

#define TPB    256
#define GROUPS 8
#define SPAN   (TPB * GROUPS)   // 2048 float4 per block

__device__ __forceinline__ void proc_elem(float pv, float rv,
                                          float s[5], float c[5], float& ov)
{
    float d = fabsf(pv - rv);
    bool geM1  = rv >= -1.0f;
    bool leM05 = rv <= -0.5f;
    bool geM05 = rv >= -0.5f;
    bool le0   = rv <=  0.0f;
    bool ge0   = rv >=  0.0f;
    bool le05  = rv <=  0.5f;
    bool ge05  = rv >=  0.5f;
    bool le1   = rv <=  1.0f;
    bool in0 = geM1  && le1;
    bool in1 = geM1  && leM05;
    bool in2 = geM05 && le0;
    bool in3 = ge0   && le05;
    bool in4 = ge05  && le1;
    s[0] += in0 ? d : 0.f;  c[0] += in0 ? 1.f : 0.f;
    s[1] += in1 ? d : 0.f;  c[1] += in1 ? 1.f : 0.f;
    s[2] += in2 ? d : 0.f;  c[2] += in2 ? 1.f : 0.f;
    s[3] += in3 ? d : 0.f;  c[3] += in3 ? 1.f : 0.f;
    s[4] += in4 ? d : 0.f;  c[4] += in4 ? 1.f : 0.f;
    // class value directly as float: -1, -.5, 0, .5, 1 (last matching wins)
    ov = in4 ? 1.0f : (in3 ? 0.5f : (in2 ? 0.0f : (in1 ? -0.5f : -1.0f)));
}

__device__ __forceinline__ void proc_group(int i, const float4& p, const float4& r,
                                           float s[5], float c[5],
                                           float* __restrict__ mask_out)
{
    float ov0, ov1, ov2, ov3;
    proc_elem(p.x, r.x, s, c, ov0);
    proc_elem(p.y, r.y, s, c, ov1);
    proc_elem(p.z, r.z, s, c, ov2);
    proc_elem(p.w, r.w, s, c, ov3);
    // mask_out = out+6: 8-byte aligned only -> float2 stores
    float2* mo = (float2*)(mask_out + 4 * (size_t)i);
    mo[0] = make_float2(ov0, ov1);
    mo[1] = make_float2(ov2, ov3);
}

__global__ __launch_bounds__(TPB, 4) void mcl_main(
    const float* __restrict__ pre, const float* __restrict__ real,
    float* __restrict__ mask_out, float* __restrict__ acc, int n4, int n)
{
    float s[5] = {0.f, 0.f, 0.f, 0.f, 0.f};
    float c[5] = {0.f, 0.f, 0.f, 0.f, 0.f};

    const int t = threadIdx.x;
    const int bid = blockIdx.x;
    const int base = bid * SPAN + t;

    const float4* pre4  = (const float4*)pre;
    const float4* real4 = (const float4*)real;

    const bool full = (bid + 1) * SPAN <= n4;   // grid divides N=16M exactly
    if (full) {
        // depth-4 rolling pipeline, every load unconditional.
        // Preload tiles 0..3; steady state issues tile k+4 before computing k.
        float4 P0 = pre4[base + 0 * TPB], R0 = real4[base + 0 * TPB];
        float4 P1 = pre4[base + 1 * TPB], R1 = real4[base + 1 * TPB];
        float4 P2 = pre4[base + 2 * TPB], R2 = real4[base + 2 * TPB];
        float4 P3 = pre4[base + 3 * TPB], R3 = real4[base + 3 * TPB];

        float4 P4 = pre4[base + 4 * TPB], R4 = real4[base + 4 * TPB];
        proc_group(base + 0 * TPB, P0, R0, s, c, mask_out);
        float4 P5 = pre4[base + 5 * TPB], R5 = real4[base + 5 * TPB];
        proc_group(base + 1 * TPB, P1, R1, s, c, mask_out);
        float4 P6 = pre4[base + 6 * TPB], R6 = real4[base + 6 * TPB];
        proc_group(base + 2 * TPB, P2, R2, s, c, mask_out);
        float4 P7 = pre4[base + 7 * TPB], R7 = real4[base + 7 * TPB];
        proc_group(base + 3 * TPB, P3, R3, s, c, mask_out);
        proc_group(base + 4 * TPB, P4, R4, s, c, mask_out);
        proc_group(base + 5 * TPB, P5, R5, s, c, mask_out);
        proc_group(base + 6 * TPB, P6, R6, s, c, mask_out);
        proc_group(base + 7 * TPB, P7, R7, s, c, mask_out);
    } else {
        // partial block (unused when SPAN | n4): guarded loop
        for (int k = 0; k < GROUPS; ++k) {
            int i = base + k * TPB;
            if (i < n4) {
                float4 p = pre4[i], r = real4[i];
                proc_group(i, p, r, s, c, mask_out);
            }
        }
    }

    // scalar tail (n not divisible by 4) — last block only
    if (bid == (int)gridDim.x - 1) {
        int tail_base = n4 * 4;
        int tail = n - tail_base;
        if (t < tail) {
            int idx = tail_base + t;
            float ov;
            proc_elem(pre[idx], real[idx], s, c, ov);
            mask_out[idx] = ov;
        }
    }

    // wave64 butterfly reduction (10 floats)
#pragma unroll
    for (int j = 0; j < 5; ++j) {
#pragma unroll
        for (int off = 32; off > 0; off >>= 1) {
            s[j] += __shfl_down(s[j], off, 64);
            c[j] += __shfl_down(c[j], off, 64);
        }
    }

    __shared__ float ls[4][5];
    __shared__ float lc[4][5];
    const int lane = t & 63;
    const int wave = t >> 6;
    if (lane == 0) {
#pragma unroll
        for (int j = 0; j < 5; ++j) { ls[wave][j] = s[j]; lc[wave][j] = c[j]; }
    }
    __syncthreads();

    // plain store of 10 partials into this block's private SoA slots.
    if (t < 10) {
        int j = (t < 5) ? t : t - 5;
        float v = (t < 5) ? (ls[0][j] + ls[1][j] + ls[2][j] + ls[3][j])
                          : (lc[0][j] + lc[1][j] + lc[2][j] + lc[3][j]);
        acc[(size_t)t * gridDim.x + bid] = v;
    }
}

__global__ __launch_bounds__(1024) void mcl_final(
    const float* __restrict__ acc, float* __restrict__ out, int nblocks)
{
    const int t = threadIdx.x;
    float sum[10];
#pragma unroll
    for (int j = 0; j < 10; ++j) sum[j] = 0.f;

    if ((nblocks & 3) == 0) {
        // vector path: plane j = nblocks contiguous floats, 16B-aligned;
        // all 10 planes batched -> 10 concurrent float4 loads per iteration
        const int n4p = nblocks >> 2;
        for (int k4 = t; k4 < n4p; k4 += 1024) {
            float4 tmp[10];
#pragma unroll
            for (int j = 0; j < 10; ++j)
                tmp[j] = ((const float4*)(acc + (size_t)j * nblocks))[k4];
#pragma unroll
            for (int j = 0; j < 10; ++j)
                sum[j] += (tmp[j].x + tmp[j].y) + (tmp[j].z + tmp[j].w);
        }
    } else {
        for (int slot = t; slot < nblocks; slot += 1024) {
#pragma unroll
            for (int j = 0; j < 10; ++j)
                sum[j] += acc[(size_t)j * nblocks + slot];
        }
    }

    // wave butterfly
#pragma unroll
    for (int j = 0; j < 10; ++j) {
#pragma unroll
        for (int off = 32; off > 0; off >>= 1)
            sum[j] += __shfl_down(sum[j], off, 64);
    }

    __shared__ float fs[16][10];
    const int lane = t & 63;
    const int wave = t >> 6;
    if (lane == 0) {
#pragma unroll
        for (int j = 0; j < 10; ++j) fs[wave][j] = sum[j];
    }
    __syncthreads();

    __shared__ float red[10];
    if (t < 10) {
        float v = 0.f;
#pragma unroll
        for (int w = 0; w < 16; ++w) v += fs[w][t];
        red[t] = v;
    }
    __syncthreads();

    if (t == 0) {
        float total = 0.f;
#pragma unroll
        for (int j = 0; j < 5; ++j) {
            float ssum = red[j];
            float csum = red[5 + j];                  // exact integer-valued float
            float denom = csum > 1.f ? csum : 1.f;    // max(count, 1)
            float lv = (csum == 0.f) ? 0.f : (ssum / denom) * 0.2f;
            out[1 + j] = lv;
            total += lv;
        }
        out[0] = total;
    }
}

extern "C" void kernel_launch(void* const* d_in, const int* in_sizes, int n_in,
                              void* d_out, int out_size, void* d_ws, size_t ws_size,
                              hipStream_t stream) {
    const float* pre  = (const float*)d_in[0];
    const float* real = (const float*)d_in[1];
    float* out = (float*)d_out;
    int n = in_sizes[0];
    int n4 = n / 4;

    int blocks = (n4 + SPAN - 1) / SPAN;           // 2048 for N=16M (exact)
    if (blocks < 1) blocks = 1;

    // d_ws: 10 planes x nblocks floats (80 KB). Every slot the final kernel
    // reads is written by mcl_main first — no memset node needed.
    float* acc = (float*)d_ws;

    mcl_main<<<blocks, TPB, 0, stream>>>(pre, real, out + 6, acc, n4, n);
    mcl_final<<<1, 1024, 0, stream>>>(acc, out, blocks);
}